// Round 1
// baseline (104.854 us; speedup 1.0000x reference)
//
#include <hip/hip_runtime.h>
#include <hip/hip_bf16.h>

typedef __bf16 bf16x8 __attribute__((ext_vector_type(8)));
typedef float f32x4 __attribute__((ext_vector_type(4)));

#define MFMA16(a, b, c) __builtin_amdgcn_mfma_f32_16x16x32_bf16((a), (b), (c), 0, 0, 0)

// ---- constants ----
#define BATCH 8
#define SEQ 512
#define HID 768
#define NHEAD 12
#define HDIM 64
#define MTOT (BATCH * SEQ)   // 4096
#define NTOT (3 * HID)       // 2304

typedef const unsigned int __attribute__((address_space(1))) *gptr_t;
typedef unsigned int __attribute__((address_space(3))) *lptr_t;

__device__ __forceinline__ unsigned short f2bf(float f) {
    unsigned int u = __float_as_uint(f);
    u += 0x7fffu + ((u >> 16) & 1u);
    return (unsigned short)(u >> 16);
}

// ---- fp32 -> bf16 converts ----
__global__ __launch_bounds__(256) void cvt_hs_kernel(const float4* __restrict__ src,
                                                     ushort4* __restrict__ dst) {
    int i = blockIdx.x * 256 + threadIdx.x;   // one float4 each; grid sized exactly
    float4 v = src[i];
    ushort4 o;
    o.x = f2bf(v.x); o.y = f2bf(v.y); o.z = f2bf(v.z); o.w = f2bf(v.w);
    dst[i] = o;
}

__global__ __launch_bounds__(256) void cvt_w_kernel(const float4* __restrict__ Wq,
                                                    const float4* __restrict__ Wk,
                                                    const float4* __restrict__ Wv,
                                                    ushort4* __restrict__ dst) {
    int which = blockIdx.y;
    const float4* src = (which == 0) ? Wq : ((which == 1) ? Wk : Wv);
    int i = blockIdx.x * 256 + threadIdx.x;   // 147456 float4 per weight, grid exact
    float4 v = src[i];
    ushort4 o;
    o.x = f2bf(v.x); o.y = f2bf(v.y); o.z = f2bf(v.z); o.w = f2bf(v.w);
    dst[(size_t)which * 147456 + i] = o;
}

// ---- fused QKV GEMM:  C[m, n] = sum_k hs[m,k] * W[n,k]  (n spans Wq|Wk|Wv rows) ----
// 128x128 tile, BK=64, 4 waves (2x2), each wave 64x64 via 4x4 MFMA 16x16x32.
__global__ __launch_bounds__(256) void qkv_gemm_kernel(const unsigned short* __restrict__ hsb,
                                                       const unsigned short* __restrict__ wb,
                                                       const float* __restrict__ bq,
                                                       const float* __restrict__ bk,
                                                       const float* __restrict__ bv,
                                                       unsigned short* __restrict__ Qb,
                                                       unsigned short* __restrict__ Kb,
                                                       unsigned short* __restrict__ VTb) {
    __shared__ __align__(16) unsigned short lsA[128 * 64];
    __shared__ __align__(16) unsigned short lsB[128 * 64];

    const int tid = threadIdx.x;
    const int w = tid >> 6;
    const int l = tid & 63;
    const int r16 = l & 15, g4 = l >> 4;
    const int wr = w >> 1, wc = w & 1;
    const int m0 = blockIdx.y * 128;
    const int n0 = blockIdx.x * 128;

    f32x4 acc[4][4];
#pragma unroll
    for (int i = 0; i < 4; ++i)
#pragma unroll
        for (int j = 0; j < 4; ++j)
            acc[i][j] = (f32x4){0.f, 0.f, 0.f, 0.f};

    for (int kt = 0; kt < 12; ++kt) {
        const int k0 = kt * 64;
        __syncthreads();
#pragma unroll
        for (int r = 0; r < 4; ++r) {
            int c = r * 256 + tid;              // 16B chunk index 0..1023
            int row = c >> 3;
            int cir = c & 7;
            const unsigned short* ga = hsb + (size_t)(m0 + row) * HID + k0 + cir * 8;
            __builtin_amdgcn_global_load_lds((gptr_t)(const void*)ga,
                                             (lptr_t)(void*)(lsA + (size_t)(r * 256 + w * 64) * 8),
                                             16, 0, 0);
            const unsigned short* gb = wb + (size_t)(n0 + row) * HID + k0 + cir * 8;
            __builtin_amdgcn_global_load_lds((gptr_t)(const void*)gb,
                                             (lptr_t)(void*)(lsB + (size_t)(r * 256 + w * 64) * 8),
                                             16, 0, 0);
        }
        __syncthreads();
#pragma unroll
        for (int kk = 0; kk < 64; kk += 32) {
            bf16x8 af[4], bfr[4];
#pragma unroll
            for (int mi = 0; mi < 4; ++mi)
                af[mi] = *reinterpret_cast<const bf16x8*>(&lsA[(wr * 64 + mi * 16 + r16) * 64 + kk + g4 * 8]);
#pragma unroll
            for (int ni = 0; ni < 4; ++ni)
                bfr[ni] = *reinterpret_cast<const bf16x8*>(&lsB[(wc * 64 + ni * 16 + r16) * 64 + kk + g4 * 8]);
#pragma unroll
            for (int mi = 0; mi < 4; ++mi)
#pragma unroll
                for (int ni = 0; ni < 4; ++ni)
                    acc[mi][ni] = MFMA16(af[mi], bfr[ni], acc[mi][ni]);
        }
    }

    // epilogue: bias add, Q pre-scale by 1/8, scatter to head layouts
#pragma unroll
    for (int ni = 0; ni < 4; ++ni) {
        int col = n0 + wc * 64 + ni * 16 + r16;   // 0..2303
        int which = col / HID;                    // 0=Q 1=K 2=V
        int oo = col - which * HID;
        int head = oo >> 6, d = oo & 63;
        const float* bias = (which == 0) ? bq : ((which == 1) ? bk : bv);
        float bvv = bias[oo];
#pragma unroll
        for (int mi = 0; mi < 4; ++mi) {
            int row0 = m0 + wr * 64 + mi * 16 + g4 * 4;   // 4-aligned, no batch straddle
            int bi = row0 >> 9;
            int s0 = row0 & 511;
            if (which == 2) {
                ushort4 pk;
                pk.x = f2bf(acc[mi][ni][0] + bvv);
                pk.y = f2bf(acc[mi][ni][1] + bvv);
                pk.z = f2bf(acc[mi][ni][2] + bvv);
                pk.w = f2bf(acc[mi][ni][3] + bvv);
                *reinterpret_cast<ushort4*>(
                    &VTb[((size_t)(bi * NHEAD + head) * HDIM + d) * SEQ + s0]) = pk;
            } else {
                unsigned short* dst = (which == 0) ? Qb : Kb;
                float scale = (which == 0) ? 0.125f : 1.0f;
#pragma unroll
                for (int r = 0; r < 4; ++r) {
                    dst[((size_t)(bi * NHEAD + head) * SEQ + (s0 + r)) * HDIM + d] =
                        f2bf((acc[mi][ni][r] + bvv) * scale);
                }
            }
        }
    }
}

// ---- attention: one workgroup per (b, h, 64 q-rows); each wave owns 16 q-rows ----
__global__ __launch_bounds__(256) void attn_kernel(const unsigned short* __restrict__ Qb,
                                                   const unsigned short* __restrict__ Kb,
                                                   const unsigned short* __restrict__ VTb,
                                                   const float* __restrict__ mask,
                                                   float* __restrict__ out) {
    __shared__ __align__(16) unsigned short lds_p[4 * 16 * 512];   // 64 KB, per-wave 16x512

    const int tid = threadIdx.x;
    const int w = tid >> 6;
    const int l = tid & 63;
    const int r16 = l & 15, g4 = l >> 4;
    const int qb = blockIdx.x, h = blockIdx.y, b = blockIdx.z;

    const size_t headoff = ((size_t)b * NHEAD + h) * SEQ * HDIM;
    const int q0 = qb * 64 + w * 16;
    char* pbuf = reinterpret_cast<char*>(lds_p + (size_t)w * 16 * 512);

    // Q fragments (Q pre-scaled by 1/8 in GEMM epilogue)
    bf16x8 qa[2];
#pragma unroll
    for (int kb = 0; kb < 2; ++kb)
        qa[kb] = *reinterpret_cast<const bf16x8*>(
            &Qb[headoff + (size_t)(q0 + r16) * HDIM + kb * 32 + g4 * 8]);

    // QK^T: 32 C-tiles of 16x16, scores in regs. C: row=q=(g4*4+reg), col=k=(kt*16+r16)
    f32x4 sc[32];
#pragma unroll
    for (int kt = 0; kt < 32; ++kt) {
        bf16x8 kf0 = *reinterpret_cast<const bf16x8*>(
            &Kb[headoff + (size_t)(kt * 16 + r16) * HDIM + g4 * 8]);
        bf16x8 kf1 = *reinterpret_cast<const bf16x8*>(
            &Kb[headoff + (size_t)(kt * 16 + r16) * HDIM + 32 + g4 * 8]);
        f32x4 c = {0.f, 0.f, 0.f, 0.f};
        c = MFMA16(qa[0], kf0, c);
        c = MFMA16(qa[1], kf1, c);
        float mval = mask[b * SEQ + kt * 16 + r16];
        c[0] += mval; c[1] += mval; c[2] += mval; c[3] += mval;
        sc[kt] = c;
    }

    // row max (over all k) per q-row
    float mx[4] = {-3.0e38f, -3.0e38f, -3.0e38f, -3.0e38f};
#pragma unroll
    for (int kt = 0; kt < 32; ++kt)
#pragma unroll
        for (int r = 0; r < 4; ++r)
            mx[r] = fmaxf(mx[r], sc[kt][r]);
#pragma unroll
    for (int off = 1; off < 16; off <<= 1)
#pragma unroll
        for (int r = 0; r < 4; ++r)
            mx[r] = fmaxf(mx[r], __shfl_xor(mx[r], off));

    // exp, row-sum, write P (bf16) to XOR-swizzled per-wave LDS
    float sum[4] = {0.f, 0.f, 0.f, 0.f};
#pragma unroll
    for (int kt = 0; kt < 32; ++kt) {
#pragma unroll
        for (int r = 0; r < 4; ++r) {
            float p = __expf(sc[kt][r] - mx[r]);
            sum[r] += p;
            int q = g4 * 4 + r;
            int kcol = kt * 16 + r16;
            int byte = q * 1024 + ((kcol * 2) ^ ((q & 7) << 4));
            *reinterpret_cast<unsigned short*>(pbuf + byte) = f2bf(p);
        }
    }
#pragma unroll
    for (int off = 1; off < 16; off <<= 1)
#pragma unroll
        for (int r = 0; r < 4; ++r)
            sum[r] += __shfl_xor(sum[r], off);

    __syncthreads();   // lgkm drain; waves use private LDS regions

    // PV: ctx[q][d] = sum_k P[q][k] * VT[d][k]
    const size_t vtoff = ((size_t)b * NHEAD + h) * HDIM * SEQ;
#pragma unroll
    for (int nt = 0; nt < 4; ++nt) {
        f32x4 ct = {0.f, 0.f, 0.f, 0.f};
#pragma unroll
        for (int kt2 = 0; kt2 < 16; ++kt2) {
            int q = r16;
            int byte = q * 1024 + ((kt2 * 64 + g4 * 16) ^ ((q & 7) << 4));
            bf16x8 pa = *reinterpret_cast<const bf16x8*>(pbuf + byte);
            bf16x8 vb = *reinterpret_cast<const bf16x8*>(
                &VTb[vtoff + (size_t)(nt * 16 + r16) * SEQ + kt2 * 32 + g4 * 8]);
            ct = MFMA16(pa, vb, ct);
        }
#pragma unroll
        for (int r = 0; r < 4; ++r) {
            int q = g4 * 4 + r;
            int s = q0 + q;
            out[((size_t)b * SEQ + s) * HID + h * HDIM + nt * 16 + r16] = ct[r] / sum[r];
        }
    }
}

extern "C" void kernel_launch(void* const* d_in, const int* in_sizes, int n_in,
                              void* d_out, int out_size, void* d_ws, size_t ws_size,
                              hipStream_t stream) {
    const float* hs   = (const float*)d_in[0];
    const float* mask = (const float*)d_in[1];
    const float* Wq   = (const float*)d_in[2];
    const float* bq   = (const float*)d_in[3];
    const float* Wk   = (const float*)d_in[4];
    const float* bk   = (const float*)d_in[5];
    const float* Wv   = (const float*)d_in[6];
    const float* bv   = (const float*)d_in[7];
    float* out = (float*)d_out;

    char* ws = (char*)d_ws;
    // ws layout (bytes): hsb 6291456 | wb 3538944 | Q 6291456 | K 6291456 | VT 6291456
    unsigned short* hsb = (unsigned short*)(ws);
    unsigned short* wb  = (unsigned short*)(ws + 6291456);
    unsigned short* Qb  = (unsigned short*)(ws + 9830400);
    unsigned short* Kb  = (unsigned short*)(ws + 16121856);
    unsigned short* VTb = (unsigned short*)(ws + 22413312);

    // hidden: 4096*768 = 3145728 floats = 786432 float4
    cvt_hs_kernel<<<3072, 256, 0, stream>>>((const float4*)hs, (ushort4*)hsb);
    // weights: 3 x 589824 floats = 3 x 147456 float4
    cvt_w_kernel<<<dim3(576, 3), 256, 0, stream>>>((const float4*)Wq, (const float4*)Wk,
                                                   (const float4*)Wv, (ushort4*)wb);
    // fused QKV GEMM: grid = (N/128, M/128) = (18, 32)
    qkv_gemm_kernel<<<dim3(18, 32), 256, 0, stream>>>(hsb, wb, bq, bk, bv, Qb, Kb, VTb);
    // attention: grid = (qblocks=8, heads=12, batch=8)
    attn_kernel<<<dim3(8, 12, 8), 256, 0, stream>>>(Qb, Kb, VTb, mask, out);
}

// Round 2
// 99.837 us; speedup vs baseline: 1.0503x; 1.0503x over previous
//
#include <hip/hip_runtime.h>
#include <hip/hip_bf16.h>

typedef __bf16 bf16x8 __attribute__((ext_vector_type(8)));
typedef float f32x4 __attribute__((ext_vector_type(4)));

#define MFMA16(a, b, c) __builtin_amdgcn_mfma_f32_16x16x32_bf16((a), (b), (c), 0, 0, 0)

// ---- constants ----
#define BATCH 8
#define SEQ 512
#define HID 768
#define NHEAD 12
#define HDIM 64
#define MTOT (BATCH * SEQ)   // 4096
#define NTOT (3 * HID)       // 2304

typedef const unsigned int __attribute__((address_space(1))) *gptr_t;
typedef unsigned int __attribute__((address_space(3))) *lptr_t;

__device__ __forceinline__ unsigned short f2bf(float f) {
    unsigned int u = __float_as_uint(f);
    u += 0x7fffu + ((u >> 16) & 1u);
    return (unsigned short)(u >> 16);
}

// ---- fused fp32 -> bf16 convert (hidden_states + 3 weights, one dispatch) ----
// hs: 786432 float4 chunks; each weight: 147456 chunks; total 1228800 = 4800 * 256
__global__ __launch_bounds__(256) void cvt_all_kernel(const float4* __restrict__ hs,
                                                      const float4* __restrict__ Wq,
                                                      const float4* __restrict__ Wk,
                                                      const float4* __restrict__ Wv,
                                                      ushort4* __restrict__ hsb,
                                                      ushort4* __restrict__ wb) {
    int i = blockIdx.x * 256 + threadIdx.x;
    float4 v;
    ushort4* dst;
    if (i < 786432) {
        v = hs[i];
        dst = hsb + i;
    } else {
        int j = i - 786432;
        int which = j / 147456;
        int jj = j - which * 147456;
        const float4* src = (which == 0) ? Wq : ((which == 1) ? Wk : Wv);
        v = src[jj];
        dst = wb + j;
    }
    ushort4 o;
    o.x = f2bf(v.x); o.y = f2bf(v.y); o.z = f2bf(v.z); o.w = f2bf(v.w);
    *dst = o;
}

// ---- fused QKV GEMM:  C[m, n] = sum_k hs[m,k] * W[n,k]  (n spans Wq|Wk|Wv rows) ----
// 128x128 tile, BK=64, 4 waves (2x2), each wave 64x64 via 4x4 MFMA 16x16x32.
__global__ __launch_bounds__(256) void qkv_gemm_kernel(const unsigned short* __restrict__ hsb,
                                                       const unsigned short* __restrict__ wb,
                                                       const float* __restrict__ bq,
                                                       const float* __restrict__ bk,
                                                       const float* __restrict__ bv,
                                                       unsigned short* __restrict__ Qb,
                                                       unsigned short* __restrict__ Kb,
                                                       unsigned short* __restrict__ VTb) {
    __shared__ __align__(16) unsigned short lsA[128 * 64];
    __shared__ __align__(16) unsigned short lsB[128 * 64];

    const int tid = threadIdx.x;
    const int w = tid >> 6;
    const int l = tid & 63;
    const int r16 = l & 15, g4 = l >> 4;
    const int wr = w >> 1, wc = w & 1;
    const int m0 = blockIdx.y * 128;
    const int n0 = blockIdx.x * 128;

    f32x4 acc[4][4];
#pragma unroll
    for (int i = 0; i < 4; ++i)
#pragma unroll
        for (int j = 0; j < 4; ++j)
            acc[i][j] = (f32x4){0.f, 0.f, 0.f, 0.f};

    for (int kt = 0; kt < 12; ++kt) {
        const int k0 = kt * 64;
        __syncthreads();
#pragma unroll
        for (int r = 0; r < 4; ++r) {
            int c = r * 256 + tid;              // 16B chunk index 0..1023
            int row = c >> 3;
            int cir = c & 7;
            const unsigned short* ga = hsb + (size_t)(m0 + row) * HID + k0 + cir * 8;
            __builtin_amdgcn_global_load_lds((gptr_t)(const void*)ga,
                                             (lptr_t)(void*)(lsA + (size_t)(r * 256 + w * 64) * 8),
                                             16, 0, 0);
            const unsigned short* gb = wb + (size_t)(n0 + row) * HID + k0 + cir * 8;
            __builtin_amdgcn_global_load_lds((gptr_t)(const void*)gb,
                                             (lptr_t)(void*)(lsB + (size_t)(r * 256 + w * 64) * 8),
                                             16, 0, 0);
        }
        __syncthreads();
#pragma unroll
        for (int kk = 0; kk < 64; kk += 32) {
            bf16x8 af[4], bfr[4];
#pragma unroll
            for (int mi = 0; mi < 4; ++mi)
                af[mi] = *reinterpret_cast<const bf16x8*>(&lsA[(wr * 64 + mi * 16 + r16) * 64 + kk + g4 * 8]);
#pragma unroll
            for (int ni = 0; ni < 4; ++ni)
                bfr[ni] = *reinterpret_cast<const bf16x8*>(&lsB[(wc * 64 + ni * 16 + r16) * 64 + kk + g4 * 8]);
#pragma unroll
            for (int mi = 0; mi < 4; ++mi)
#pragma unroll
                for (int ni = 0; ni < 4; ++ni)
                    acc[mi][ni] = MFMA16(af[mi], bfr[ni], acc[mi][ni]);
        }
    }

    // epilogue: bias add, Q pre-scale by 1/8, scatter to head layouts
#pragma unroll
    for (int ni = 0; ni < 4; ++ni) {
        int col = n0 + wc * 64 + ni * 16 + r16;   // 0..2303
        int which = col / HID;                    // 0=Q 1=K 2=V
        int oo = col - which * HID;
        int head = oo >> 6, d = oo & 63;
        const float* bias = (which == 0) ? bq : ((which == 1) ? bk : bv);
        float bvv = bias[oo];
#pragma unroll
        for (int mi = 0; mi < 4; ++mi) {
            int row0 = m0 + wr * 64 + mi * 16 + g4 * 4;   // 4-aligned, no batch straddle
            int bi = row0 >> 9;
            int s0 = row0 & 511;
            if (which == 2) {
                ushort4 pk;
                pk.x = f2bf(acc[mi][ni][0] + bvv);
                pk.y = f2bf(acc[mi][ni][1] + bvv);
                pk.z = f2bf(acc[mi][ni][2] + bvv);
                pk.w = f2bf(acc[mi][ni][3] + bvv);
                *reinterpret_cast<ushort4*>(
                    &VTb[((size_t)(bi * NHEAD + head) * HDIM + d) * SEQ + s0]) = pk;
            } else {
                unsigned short* dst = (which == 0) ? Qb : Kb;
                float scale = (which == 0) ? 0.125f : 1.0f;
#pragma unroll
                for (int r = 0; r < 4; ++r) {
                    dst[((size_t)(bi * NHEAD + head) * SEQ + (s0 + r)) * HDIM + d] =
                        f2bf((acc[mi][ni][r] + bvv) * scale);
                }
            }
        }
    }
}

// ---- attention: fused online-softmax over 4 KV-chunks of 128 ----
// grid (qb=8, h=12, b=8), 4 waves/block, each wave owns 16 q-rows.
// LDS: per-wave 16x128 bf16 P-tile (4 KB) -> 16 KB/block. No __syncthreads.
__global__ __launch_bounds__(256) void attn_kernel(const unsigned short* __restrict__ Qb,
                                                   const unsigned short* __restrict__ Kb,
                                                   const unsigned short* __restrict__ VTb,
                                                   const float* __restrict__ mask,
                                                   float* __restrict__ out) {
    __shared__ __align__(16) char pbuf_all[4 * 16 * 256];   // 16 KB total

    const int tid = threadIdx.x;
    const int w = tid >> 6;
    const int l = tid & 63;
    const int r16 = l & 15, g4 = l >> 4;
    const int qb = blockIdx.x, h = blockIdx.y, b = blockIdx.z;

    const size_t headoff = ((size_t)b * NHEAD + h) * SEQ * HDIM;
    const size_t vtoff   = ((size_t)b * NHEAD + h) * HDIM * SEQ;
    const int q0 = qb * 64 + w * 16;
    char* pbuf = pbuf_all + (size_t)w * 16 * 256;

    // Q fragments (Q pre-scaled by 1/8 in GEMM epilogue)
    bf16x8 qa0 = *reinterpret_cast<const bf16x8*>(&Qb[headoff + (size_t)(q0 + r16) * HDIM + g4 * 8]);
    bf16x8 qa1 = *reinterpret_cast<const bf16x8*>(&Qb[headoff + (size_t)(q0 + r16) * HDIM + 32 + g4 * 8]);

    float m[4] = {-3.0e38f, -3.0e38f, -3.0e38f, -3.0e38f};
    float s[4] = {0.f, 0.f, 0.f, 0.f};
    f32x4 ct[4];
#pragma unroll
    for (int nt = 0; nt < 4; ++nt) ct[nt] = (f32x4){0.f, 0.f, 0.f, 0.f};

#pragma unroll 1
    for (int ch = 0; ch < 4; ++ch) {
        // --- scores for this 128-wide chunk: 8 tiles of 16x16 ---
        f32x4 sc[8];
#pragma unroll
        for (int t = 0; t < 8; ++t) {
            int krow = ch * 128 + t * 16 + r16;
            bf16x8 kf0 = *reinterpret_cast<const bf16x8*>(&Kb[headoff + (size_t)krow * HDIM + g4 * 8]);
            bf16x8 kf1 = *reinterpret_cast<const bf16x8*>(&Kb[headoff + (size_t)krow * HDIM + 32 + g4 * 8]);
            f32x4 c = {0.f, 0.f, 0.f, 0.f};
            c = MFMA16(qa0, kf0, c);
            c = MFMA16(qa1, kf1, c);
            float mval = mask[b * SEQ + krow];
            c[0] += mval; c[1] += mval; c[2] += mval; c[3] += mval;
            sc[t] = c;
        }

        // --- chunk max per q-row, reduce across the 16 k-lanes ---
        float pm[4] = {-3.0e38f, -3.0e38f, -3.0e38f, -3.0e38f};
#pragma unroll
        for (int t = 0; t < 8; ++t)
#pragma unroll
            for (int r = 0; r < 4; ++r)
                pm[r] = fmaxf(pm[r], sc[t][r]);
#pragma unroll
        for (int off = 1; off < 16; off <<= 1)
#pragma unroll
            for (int r = 0; r < 4; ++r)
                pm[r] = fmaxf(pm[r], __shfl_xor(pm[r], off));

        float f[4];
#pragma unroll
        for (int r = 0; r < 4; ++r) {
            float mn = fmaxf(m[r], pm[r]);
            f[r] = __expf(m[r] - mn);
            m[r] = mn;
        }

        // --- exp, partial row-sums, write P (bf16) to XOR-swizzled per-wave LDS ---
        float loc[4] = {0.f, 0.f, 0.f, 0.f};
#pragma unroll
        for (int t = 0; t < 8; ++t) {
#pragma unroll
            for (int r = 0; r < 4; ++r) {
                float p = __expf(sc[t][r] - m[r]);
                loc[r] += p;
                int q = g4 * 4 + r;
                int kk = t * 16 + r16;
                int byte = q * 256 + ((kk * 2) ^ ((q & 7) << 4));
                *reinterpret_cast<unsigned short*>(pbuf + byte) = f2bf(p);
            }
        }
#pragma unroll
        for (int r = 0; r < 4; ++r) s[r] = s[r] * f[r] + loc[r];

        // --- rescale running ctx ---
#pragma unroll
        for (int nt = 0; nt < 4; ++nt) {
            ct[nt][0] *= f[0]; ct[nt][1] *= f[1]; ct[nt][2] *= f[2]; ct[nt][3] *= f[3];
        }

        // --- PV for this chunk ---
#pragma unroll
        for (int kt2 = 0; kt2 < 4; ++kt2) {
            int byte = r16 * 256 + ((kt2 * 64 + g4 * 16) ^ ((r16 & 7) << 4));
            bf16x8 pa = *reinterpret_cast<const bf16x8*>(pbuf + byte);
#pragma unroll
            for (int nt = 0; nt < 4; ++nt) {
                bf16x8 vb = *reinterpret_cast<const bf16x8*>(
                    &VTb[vtoff + (size_t)(nt * 16 + r16) * SEQ + ch * 128 + kt2 * 32 + g4 * 8]);
                ct[nt] = MFMA16(pa, vb, ct[nt]);
            }
        }
    }

    // --- final row-sum reduce + normalized output ---
#pragma unroll
    for (int off = 1; off < 16; off <<= 1)
#pragma unroll
        for (int r = 0; r < 4; ++r)
            s[r] += __shfl_xor(s[r], off);
    float rs[4];
#pragma unroll
    for (int r = 0; r < 4; ++r) rs[r] = 1.0f / s[r];

#pragma unroll
    for (int nt = 0; nt < 4; ++nt) {
#pragma unroll
        for (int r = 0; r < 4; ++r) {
            int srow = q0 + g4 * 4 + r;
            out[((size_t)b * SEQ + srow) * HID + h * HDIM + nt * 16 + r16] = ct[nt][r] * rs[r];
        }
    }
}

extern "C" void kernel_launch(void* const* d_in, const int* in_sizes, int n_in,
                              void* d_out, int out_size, void* d_ws, size_t ws_size,
                              hipStream_t stream) {
    const float* hs   = (const float*)d_in[0];
    const float* mask = (const float*)d_in[1];
    const float* Wq   = (const float*)d_in[2];
    const float* bq   = (const float*)d_in[3];
    const float* Wk   = (const float*)d_in[4];
    const float* bk   = (const float*)d_in[5];
    const float* Wv   = (const float*)d_in[6];
    const float* bv   = (const float*)d_in[7];
    float* out = (float*)d_out;

    char* ws = (char*)d_ws;
    // ws layout (bytes): hsb 6291456 | wb 3538944 | Q 6291456 | K 6291456 | VT 6291456
    unsigned short* hsb = (unsigned short*)(ws);
    unsigned short* wb  = (unsigned short*)(ws + 6291456);
    unsigned short* Qb  = (unsigned short*)(ws + 9830400);
    unsigned short* Kb  = (unsigned short*)(ws + 16121856);
    unsigned short* VTb = (unsigned short*)(ws + 22413312);

    // fused converts: 786432 + 442368 = 1228800 float4 chunks = 4800 blocks
    cvt_all_kernel<<<4800, 256, 0, stream>>>((const float4*)hs, (const float4*)Wq,
                                             (const float4*)Wk, (const float4*)Wv,
                                             (ushort4*)hsb, (ushort4*)wb);
    // fused QKV GEMM: grid = (N/128, M/128) = (18, 32)
    qkv_gemm_kernel<<<dim3(18, 32), 256, 0, stream>>>(hsb, wb, bq, bk, bv, Qb, Kb, VTb);
    // attention: grid = (qblocks=8, heads=12, batch=8)
    attn_kernel<<<dim3(8, 12, 8), 256, 0, stream>>>(Qb, Kb, VTb, mask, out);
}